// Round 1
// baseline (1250.900 us; speedup 1.0000x reference)
//
#include <hip/hip_runtime.h>
#include <hip/hip_bf16.h>
#include <math.h>

// ---------------- problem constants ----------------
#define N_NODES 10000
#define N_EDGES0 160000
#define E_TOT (N_EDGES0 + N_NODES)   // + self loops
#define H1 4
#define C1 512
#define F1 2048                      // H1*C1
#define IN_DIM 768
#define C2 768
#define NEG_SLOPE 0.2f

// Monotonic float<->unsigned encoding so atomicMax works for signed floats.
static __device__ __forceinline__ unsigned enc_f(float v) {
  unsigned u = __float_as_uint(v);
  return (u & 0x80000000u) ? ~u : (u | 0x80000000u);
}
static __device__ __forceinline__ float dec_f(unsigned u) {
  return (u & 0x80000000u) ? __uint_as_float(u ^ 0x80000000u)
                           : __uint_as_float(~u);
}

// edge e -> (src, dst); e >= N_EDGES0 are the implicit self-loops
static __device__ __forceinline__ void edge_sd(const int* __restrict__ ei, int e,
                                               int& s, int& d) {
  if (e < N_EDGES0) { s = ei[e]; d = ei[N_EDGES0 + e]; }
  else { s = e - N_EDGES0; d = s; }
}

// ---------------- fp32 tiled GEMM: C[M,N] = A[M,K] @ B[K,N] ----------------
// 128x128 tile, BK=16, 256 threads, 8x8 per thread. M-guard only
// (N, K always multiples of 128 / 16 for our shapes).
__global__ __launch_bounds__(256) void gemm128(const float* __restrict__ A,
                                               const float* __restrict__ B,
                                               float* __restrict__ C,
                                               int M, int N, int K) {
  __shared__ float As[16][128];
  __shared__ float Bs[16][128];
  const int t = threadIdx.x;
  const int m0 = blockIdx.y * 128, n0 = blockIdx.x * 128;
  const int ar = t >> 1, akc = (t & 1) * 8;       // A: 2 threads per row, 8 k each
  const int br = t >> 4, bc = (t & 15) * 8;       // B: 16 threads per row, 8 n each
  const int ty = t >> 4, tx = t & 15;

  float acc[8][8];
#pragma unroll
  for (int i = 0; i < 8; i++)
#pragma unroll
    for (int j = 0; j < 8; j++) acc[i][j] = 0.f;

  const bool avalid = (m0 + ar) < M;
  const float* Aptr = A + (size_t)(m0 + ar) * K + akc;
  const float* Bptr = B + (size_t)br * N + n0 + bc;

  for (int k0 = 0; k0 < K; k0 += 16) {
    float4 a0, a1, b0, b1;
    if (avalid) {
      a0 = *(const float4*)(Aptr + k0);
      a1 = *(const float4*)(Aptr + k0 + 4);
    } else {
      a0 = make_float4(0.f, 0.f, 0.f, 0.f); a1 = a0;
    }
    b0 = *(const float4*)(Bptr + (size_t)k0 * N);
    b1 = *(const float4*)(Bptr + (size_t)k0 * N + 4);
    __syncthreads();  // previous compute done before overwriting LDS
    As[akc + 0][ar] = a0.x; As[akc + 1][ar] = a0.y;
    As[akc + 2][ar] = a0.z; As[akc + 3][ar] = a0.w;
    As[akc + 4][ar] = a1.x; As[akc + 5][ar] = a1.y;
    As[akc + 6][ar] = a1.z; As[akc + 7][ar] = a1.w;
    *(float4*)&Bs[br][bc]     = b0;
    *(float4*)&Bs[br][bc + 4] = b1;
    __syncthreads();
#pragma unroll
    for (int k = 0; k < 16; k++) {
      float a[8], b[8];
      *(float4*)&a[0] = *(const float4*)&As[k][ty * 8];
      *(float4*)&a[4] = *(const float4*)&As[k][ty * 8 + 4];
      *(float4*)&b[0] = *(const float4*)&Bs[k][tx * 8];
      *(float4*)&b[4] = *(const float4*)&Bs[k][tx * 8 + 4];
#pragma unroll
      for (int i = 0; i < 8; i++)
#pragma unroll
        for (int j = 0; j < 8; j++) acc[i][j] = fmaf(a[i], b[j], acc[i][j]);
    }
  }
#pragma unroll
  for (int i = 0; i < 8; i++) {
    int m = m0 + ty * 8 + i;
    if (m < M) {
      float* cp = C + (size_t)m * N + n0 + tx * 8;
      *(float4*)cp       = *(float4*)&acc[i][0];
      *(float4*)(cp + 4) = *(float4*)&acc[i][4];
    }
  }
}

// ---------------- attention logits: als/ald[n,h] = <h[n,h,:], a_src/dst[h,:]> ----
__global__ void attn_logits(const float* __restrict__ h,
                            const float* __restrict__ asrc,
                            const float* __restrict__ adst,
                            float* __restrict__ als, float* __restrict__ ald,
                            int NH, int Hh, int C) {
  int w = (blockIdx.x * blockDim.x + threadIdx.x) >> 6;  // one wave per (n,h)
  int lane = threadIdx.x & 63;
  if (w >= NH) return;
  int hh = w % Hh;
  const float* hp = h + (size_t)w * C;
  const float* sp = asrc + hh * C;
  const float* dp = adst + hh * C;
  float ss = 0.f, sd = 0.f;
  for (int c = lane; c < C; c += 64) {
    float v = hp[c];
    ss = fmaf(v, sp[c], ss);
    sd = fmaf(v, dp[c], sd);
  }
#pragma unroll
  for (int o = 32; o; o >>= 1) {
    ss += __shfl_xor(ss, o);
    sd += __shfl_xor(sd, o);
  }
  if (lane == 0) { als[w] = ss; ald[w] = sd; }
}

// ---------------- edge softmax passes ----------------
__global__ void edge_max_k(const int* __restrict__ ei,
                           const float* __restrict__ als,
                           const float* __restrict__ ald,
                           float* __restrict__ ev, unsigned* __restrict__ menc,
                           int Hh) {
  int idx = blockIdx.x * blockDim.x + threadIdx.x;
  if (idx >= E_TOT * Hh) return;
  int e = idx / Hh, hh = idx - e * Hh;
  int s, d; edge_sd(ei, e, s, d);
  float x = als[s * Hh + hh] + ald[d * Hh + hh];
  float v = x > 0.f ? x : NEG_SLOPE * x;   // leaky_relu
  ev[idx] = v;
  atomicMax(&menc[d * Hh + hh], enc_f(v));
}

__global__ void edge_exp_k(const int* __restrict__ ei,
                           const unsigned* __restrict__ menc,
                           float* __restrict__ ev, float* __restrict__ denom,
                           int Hh) {
  int idx = blockIdx.x * blockDim.x + threadIdx.x;
  if (idx >= E_TOT * Hh) return;
  int e = idx / Hh, hh = idx - e * Hh;
  int s, d; edge_sd(ei, e, s, d);
  float m = dec_f(menc[d * Hh + hh]);
  float ex = expf(ev[idx] - m);
  ev[idx] = ex;
  atomicAdd(&denom[d * Hh + hh], ex);
}

// ---------------- CSR build (dst-sorted) ----------------
__global__ void hist_k(const int* __restrict__ ei, int* __restrict__ count) {
  int e = blockIdx.x * blockDim.x + threadIdx.x;
  if (e >= E_TOT) return;
  int s, d; edge_sd(ei, e, s, d);
  atomicAdd(&count[d], 1);
}

__global__ __launch_bounds__(1024) void scan_k(const int* __restrict__ count,
                                               int* __restrict__ rowstart,
                                               int N, int total) {
  __shared__ int sums[1024];
  __shared__ int carry_s;
  int t = threadIdx.x;
  if (t == 0) carry_s = 0;
  __syncthreads();
  for (int base = 0; base < N; base += 1024) {
    int i = base + t;
    int c = (i < N) ? count[i] : 0;
    sums[t] = c;
    __syncthreads();
    for (int off = 1; off < 1024; off <<= 1) {
      int v = (t >= off) ? sums[t - off] : 0;
      __syncthreads();
      sums[t] += v;
      __syncthreads();
    }
    int carry = carry_s;
    if (i < N) rowstart[i] = carry + sums[t] - c;  // exclusive
    __syncthreads();
    if (t == 1023) carry_s = carry + sums[1023];
    __syncthreads();
  }
  if (t == 0) rowstart[N] = total;
}

__global__ void scatter_k(const int* __restrict__ ei,
                          const int* __restrict__ rowstart,
                          int* __restrict__ cursor,
                          int* __restrict__ csr_src, int* __restrict__ csr_eid) {
  int e = blockIdx.x * blockDim.x + threadIdx.x;
  if (e >= E_TOT) return;
  int s, d; edge_sd(ei, e, s, d);
  int pos = rowstart[d] + atomicAdd(&cursor[d], 1);
  csr_src[pos] = s;
  csr_eid[pos] = e;
}

// ---------------- aggregation: out[n,:] = sum_in alpha * h[src,:] (+bias, act) ----
template <int FT, bool ELU>
__global__ void aggregate_k(const float* __restrict__ hsrc,
                            const float* __restrict__ ev,
                            const float* __restrict__ denom,
                            const float* __restrict__ bias,
                            const int* __restrict__ rowstart,
                            const int* __restrict__ csr_src,
                            const int* __restrict__ csr_eid,
                            float* __restrict__ out, int Hh, int C) {
  const int n = blockIdx.x;
  const int t = threadIdx.x;
  const int F = Hh * C;
  const int f0 = t * FT;
  const int hh = f0 / C;                       // FT divides C -> no straddle
  const float inv = 1.f / (denom[n * Hh + hh] + 1e-16f);
  float acc[FT];
#pragma unroll
  for (int i = 0; i < FT; i++) acc[i] = 0.f;
  const int j0 = rowstart[n], j1 = rowstart[n + 1];
  for (int j = j0; j < j1; j++) {
    int s = csr_src[j];
    int eid = csr_eid[j];
    float w = ev[eid * Hh + hh] * inv;
    const float* hp = hsrc + (size_t)s * F + f0;
#pragma unroll
    for (int i = 0; i < FT; i += 4) {
      float4 v = *(const float4*)(hp + i);
      acc[i]     = fmaf(w, v.x, acc[i]);
      acc[i + 1] = fmaf(w, v.y, acc[i + 1]);
      acc[i + 2] = fmaf(w, v.z, acc[i + 2]);
      acc[i + 3] = fmaf(w, v.w, acc[i + 3]);
    }
  }
#pragma unroll
  for (int i = 0; i < FT; i++) {
    float o = acc[i] + bias[f0 + i];
    if (ELU) o = o > 0.f ? o : expm1f(o);
    out[(size_t)n * F + f0 + i] = o;
  }
}

// ---------------- launch ----------------
extern "C" void kernel_launch(void* const* d_in, const int* in_sizes, int n_in,
                              void* d_out, int out_size, void* d_ws, size_t ws_size,
                              hipStream_t stream) {
  const float* x   = (const float*)d_in[0];
  const int*   ei  = (const int*)d_in[1];   // [2, 160000]; JAX x64 off -> int32
  const float* W1  = (const float*)d_in[2];
  const float* as1 = (const float*)d_in[3];
  const float* ad1 = (const float*)d_in[4];
  const float* b1  = (const float*)d_in[5];
  const float* W2  = (const float*)d_in[6];
  const float* as2 = (const float*)d_in[7];
  const float* ad2 = (const float*)d_in[8];
  const float* b2  = (const float*)d_in[9];
  float* out = (float*)d_out;

  // bump allocator on workspace (everything rebuilt every call; ws is poisoned)
  char* p = (char*)d_ws;
  auto alloc = [&](size_t bytes) {
    char* r = p;
    p += (bytes + 255) & ~(size_t)255;
    return r;
  };
  float*    h1       = (float*)alloc((size_t)N_NODES * F1 * 4);  // 81.9 MB
  float*    h2       = (float*)alloc((size_t)N_NODES * F1 * 4);  // 81.9 MB
  float*    als      = (float*)alloc((size_t)N_NODES * H1 * 4);
  float*    ald      = (float*)alloc((size_t)N_NODES * H1 * 4);
  unsigned* menc     = (unsigned*)alloc((size_t)N_NODES * H1 * 4);
  float*    denom    = (float*)alloc((size_t)N_NODES * H1 * 4);
  float*    ev       = (float*)alloc((size_t)E_TOT * H1 * 4);
  int*      count    = (int*)alloc((size_t)N_NODES * 4);
  int*      rowstart = (int*)alloc((size_t)(N_NODES + 1) * 4);
  int*      cursor   = (int*)alloc((size_t)N_NODES * 4);
  int*      csr_src  = (int*)alloc((size_t)E_TOT * 4);
  int*      csr_eid  = (int*)alloc((size_t)E_TOT * 4);
  float*    h3 = h1;  // h1 dead after layer-1 aggregation; alias

  const int EB = (E_TOT + 255) / 256;

  // CSR by destination (same graph both layers)
  hipMemsetAsync(count, 0, (size_t)N_NODES * 4, stream);
  hipMemsetAsync(cursor, 0, (size_t)N_NODES * 4, stream);
  hist_k<<<EB, 256, 0, stream>>>(ei, count);
  scan_k<<<1, 1024, 0, stream>>>(count, rowstart, N_NODES, E_TOT);
  scatter_k<<<EB, 256, 0, stream>>>(ei, rowstart, cursor, csr_src, csr_eid);

  // ---- layer 1 ----
  gemm128<<<dim3(F1 / 128, (N_NODES + 127) / 128), 256, 0, stream>>>(
      x, W1, h1, N_NODES, F1, IN_DIM);
  attn_logits<<<(N_NODES * H1) / 4, 256, 0, stream>>>(h1, as1, ad1, als, ald,
                                                      N_NODES * H1, H1, C1);
  hipMemsetAsync(menc, 0, (size_t)N_NODES * H1 * 4, stream);
  hipMemsetAsync(denom, 0, (size_t)N_NODES * H1 * 4, stream);
  edge_max_k<<<(E_TOT * H1 + 255) / 256, 256, 0, stream>>>(ei, als, ald, ev, menc, H1);
  edge_exp_k<<<(E_TOT * H1 + 255) / 256, 256, 0, stream>>>(ei, menc, ev, denom, H1);
  aggregate_k<8, true><<<N_NODES, 256, 0, stream>>>(h1, ev, denom, b1, rowstart,
                                                    csr_src, csr_eid, h2, H1, C1);

  // ---- layer 2 ----
  gemm128<<<dim3(C2 / 128, (N_NODES + 127) / 128), 256, 0, stream>>>(
      h2, W2, h3, N_NODES, C2, F1);
  attn_logits<<<N_NODES / 4, 256, 0, stream>>>(h3, as2, ad2, als, ald,
                                               N_NODES, 1, C2);
  hipMemsetAsync(menc, 0, (size_t)N_NODES * 4, stream);
  hipMemsetAsync(denom, 0, (size_t)N_NODES * 4, stream);
  edge_max_k<<<EB, 256, 0, stream>>>(ei, als, ald, ev, menc, 1);
  edge_exp_k<<<EB, 256, 0, stream>>>(ei, menc, ev, denom, 1);
  aggregate_k<4, false><<<N_NODES, 192, 0, stream>>>(h3, ev, denom, b2, rowstart,
                                                     csr_src, csr_eid, out, 1, C2);
}

// Round 2
// 722.987 us; speedup vs baseline: 1.7302x; 1.7302x over previous
//
#include <hip/hip_runtime.h>
#include <hip/hip_bf16.h>
#include <math.h>

// ---------------- problem constants ----------------
#define N_NODES 10000
#define N_EDGES0 160000
#define E_TOT (N_EDGES0 + N_NODES)   // + self loops
#define H1 4
#define C1 512
#define F1 2048                      // H1*C1
#define IN_DIM 768
#define C2 768
#define NEG_SLOPE 0.2f

typedef _Float16 f16x8 __attribute__((ext_vector_type(8)));
typedef _Float16 f16x4 __attribute__((ext_vector_type(4)));
typedef float f32x4 __attribute__((ext_vector_type(4)));

typedef __attribute__((address_space(1))) const void* gas_ptr;
typedef __attribute__((address_space(3))) void* las_ptr;
static __device__ __forceinline__ void gload16(const void* g, void* l) {
  __builtin_amdgcn_global_load_lds((gas_ptr)g, (las_ptr)l, 16, 0, 0);
}

// Monotonic float<->unsigned encoding so atomicMax works for signed floats.
static __device__ __forceinline__ unsigned enc_f(float v) {
  unsigned u = __float_as_uint(v);
  return (u & 0x80000000u) ? ~u : (u | 0x80000000u);
}
static __device__ __forceinline__ float dec_f(unsigned u) {
  return (u & 0x80000000u) ? __uint_as_float(u ^ 0x80000000u)
                           : __uint_as_float(~u);
}

// edge e -> (src, dst); e >= N_EDGES0 are the implicit self-loops
static __device__ __forceinline__ void edge_sd(const int* __restrict__ ei, int e,
                                               int& s, int& d) {
  if (e < N_EDGES0) { s = ei[e]; d = ei[N_EDGES0 + e]; }
  else { s = e - N_EDGES0; d = s; }
}

// ---------------- fp32 -> f16 hi/lo split (elementwise, float4) -------------
__global__ void split_k(const float* __restrict__ in, _Float16* __restrict__ hi,
                        _Float16* __restrict__ lo, int n4) {
  int i = blockIdx.x * blockDim.x + threadIdx.x;
  if (i >= n4) return;
  float4 v = ((const float4*)in)[i];
  f16x4 h, l;
  h.x = (_Float16)v.x; l.x = (_Float16)(v.x - (float)h.x);
  h.y = (_Float16)v.y; l.y = (_Float16)(v.y - (float)h.y);
  h.z = (_Float16)v.z; l.z = (_Float16)(v.z - (float)h.z);
  h.w = (_Float16)v.w; l.w = (_Float16)(v.w - (float)h.w);
  ((f16x4*)hi)[i] = h;
  ((f16x4*)lo)[i] = l;
}

// ---------------- W [K][N] fp32 -> W^T [N][K] f16 hi/lo ---------------------
__global__ void tsplit_k(const float* __restrict__ W, _Float16* __restrict__ hi,
                         _Float16* __restrict__ lo, int K, int N) {
  __shared__ float tile[32][33];
  const int nb = blockIdx.x * 32, kb = blockIdx.y * 32;
  const int tx = threadIdx.x, ty = threadIdx.y;  // 32 x 8
  for (int r = ty; r < 32; r += 8)
    tile[r][tx] = W[(size_t)(kb + r) * N + nb + tx];
  __syncthreads();
  for (int r = ty; r < 32; r += 8) {
    float v = tile[tx][r];  // = W[kb+tx][nb+r]
    _Float16 h = (_Float16)v;
    hi[(size_t)(nb + r) * K + kb + tx] = h;
    lo[(size_t)(nb + r) * K + kb + tx] = (_Float16)(v - (float)h);
  }
}

// ---------------- split-f16 MFMA GEMM: C[M,N] = A[M,K] @ Bt[N,K]^T ----------
// 128x128 tile, BK=32, 4 waves, each wave 64x64 (4x4 16x16 frags).
// 3 MFMA passes: hi*hi + hi*lo + lo*hi  (~fp32 accuracy).
__global__ __launch_bounds__(256) void gemm_sf16(
    const _Float16* __restrict__ Ahi, const _Float16* __restrict__ Alo,
    const _Float16* __restrict__ Bhi, const _Float16* __restrict__ Blo,
    float* __restrict__ C, int M, int N, int K) {
  __shared__ _Float16 sAh[128 * 32];
  __shared__ _Float16 sAl[128 * 32];
  __shared__ _Float16 sBh[128 * 32];
  __shared__ _Float16 sBl[128 * 32];

  const int t = threadIdx.x;
  const int w = t >> 6, lane = t & 63;
  const int m0 = blockIdx.y * 128, n0 = blockIdx.x * 128;

  // staging decomposition: chunk i covers LDS bytes [w*1024 + i*4096, +1024)
  const int o0 = w * 1024 + lane * 16;
  const int o1 = o0 + 4096;
  const int ma0 = o0 >> 6, cb0 = o0 & 63;  // row, byte-in-row (64B rows)
  const int ma1 = o1 >> 6, cb1 = o1 & 63;
  const int rA0 = min(m0 + ma0, M - 1), rA1 = min(m0 + ma1, M - 1);
  const size_t gA0 = (size_t)rA0 * K + (cb0 >> 1);
  const size_t gA1 = (size_t)rA1 * K + (cb1 >> 1);
  const size_t gB0 = (size_t)(n0 + ma0) * K + (cb0 >> 1);
  const size_t gB1 = (size_t)(n0 + ma1) * K + (cb1 >> 1);

  char* lA0 = (char*)sAh + w * 1024;           // wave-uniform LDS bases
  char* lA1 = lA0 + 4096;
  char* lAl0 = (char*)sAl + w * 1024;
  char* lAl1 = lAl0 + 4096;
  char* lB0 = (char*)sBh + w * 1024;
  char* lB1 = lB0 + 4096;
  char* lBl0 = (char*)sBl + w * 1024;
  char* lBl1 = lBl0 + 4096;

  // fragment read offsets (f16 elements)
  const int wr = w >> 1, wc = w & 1;
  const int lr = lane & 15, lg = lane >> 4;
  const int aoff = (wr * 64 + lr) * 32 + lg * 8;
  const int boff = (wc * 64 + lr) * 32 + lg * 8;

  f32x4 acc[4][4];
#pragma unroll
  for (int i = 0; i < 4; i++)
#pragma unroll
    for (int j = 0; j < 4; j++) acc[i][j] = (f32x4)(0.f);

  for (int k0 = 0; k0 < K; k0 += 32) {
    __syncthreads();  // previous iter's ds_reads done before overwrite
    gload16(Ahi + gA0 + k0, lA0);
    gload16(Ahi + gA1 + k0, lA1);
    gload16(Alo + gA0 + k0, lAl0);
    gload16(Alo + gA1 + k0, lAl1);
    gload16(Bhi + gB0 + k0, lB0);
    gload16(Bhi + gB1 + k0, lB1);
    gload16(Blo + gB0 + k0, lBl0);
    gload16(Blo + gB1 + k0, lBl1);
    __syncthreads();  // barrier drains vmcnt -> tiles ready

    f16x8 ah[4], al[4], bh[4], bl[4];
#pragma unroll
    for (int i = 0; i < 4; i++) {
      ah[i] = *(const f16x8*)&sAh[aoff + i * 16 * 32];
      al[i] = *(const f16x8*)&sAl[aoff + i * 16 * 32];
      bh[i] = *(const f16x8*)&sBh[boff + i * 16 * 32];
      bl[i] = *(const f16x8*)&sBl[boff + i * 16 * 32];
    }
#pragma unroll
    for (int i = 0; i < 4; i++)
#pragma unroll
      for (int j = 0; j < 4; j++) {
        acc[i][j] = __builtin_amdgcn_mfma_f32_16x16x32_f16(ah[i], bh[j], acc[i][j], 0, 0, 0);
        acc[i][j] = __builtin_amdgcn_mfma_f32_16x16x32_f16(ah[i], bl[j], acc[i][j], 0, 0, 0);
        acc[i][j] = __builtin_amdgcn_mfma_f32_16x16x32_f16(al[i], bh[j], acc[i][j], 0, 0, 0);
      }
  }

  // C/D layout: col = lane&15, row = (lane>>4)*4 + reg  [m89/m91 verified]
#pragma unroll
  for (int i = 0; i < 4; i++)
#pragma unroll
    for (int j = 0; j < 4; j++) {
      const int col = n0 + wc * 64 + j * 16 + lr;
      const int rbase = m0 + wr * 64 + i * 16 + lg * 4;
#pragma unroll
      for (int r = 0; r < 4; r++) {
        int row = rbase + r;
        if (row < M) C[(size_t)row * N + col] = acc[i][j][r];
      }
    }
}

// ---------------- attention logits: als/ald[n,h] = <h[n,h,:], a_src/dst[h,:]> ----
__global__ void attn_logits(const float* __restrict__ h,
                            const float* __restrict__ asrc,
                            const float* __restrict__ adst,
                            float* __restrict__ als, float* __restrict__ ald,
                            int NH, int Hh, int C) {
  int w = (blockIdx.x * blockDim.x + threadIdx.x) >> 6;  // one wave per (n,h)
  int lane = threadIdx.x & 63;
  if (w >= NH) return;
  int hh = w % Hh;
  const float* hp = h + (size_t)w * C;
  const float* sp = asrc + hh * C;
  const float* dp = adst + hh * C;
  float ss = 0.f, sd = 0.f;
  for (int c = lane; c < C; c += 64) {
    float v = hp[c];
    ss = fmaf(v, sp[c], ss);
    sd = fmaf(v, dp[c], sd);
  }
#pragma unroll
  for (int o = 32; o; o >>= 1) {
    ss += __shfl_xor(ss, o);
    sd += __shfl_xor(sd, o);
  }
  if (lane == 0) { als[w] = ss; ald[w] = sd; }
}

// ---------------- edge softmax passes ----------------
__global__ void edge_max_k(const int* __restrict__ ei,
                           const float* __restrict__ als,
                           const float* __restrict__ ald,
                           float* __restrict__ ev, unsigned* __restrict__ menc,
                           int Hh) {
  int idx = blockIdx.x * blockDim.x + threadIdx.x;
  if (idx >= E_TOT * Hh) return;
  int e = idx / Hh, hh = idx - e * Hh;
  int s, d; edge_sd(ei, e, s, d);
  float x = als[s * Hh + hh] + ald[d * Hh + hh];
  float v = x > 0.f ? x : NEG_SLOPE * x;   // leaky_relu
  ev[idx] = v;
  atomicMax(&menc[d * Hh + hh], enc_f(v));
}

__global__ void edge_exp_k(const int* __restrict__ ei,
                           const unsigned* __restrict__ menc,
                           float* __restrict__ ev, float* __restrict__ denom,
                           int Hh) {
  int idx = blockIdx.x * blockDim.x + threadIdx.x;
  if (idx >= E_TOT * Hh) return;
  int e = idx / Hh, hh = idx - e * Hh;
  int s, d; edge_sd(ei, e, s, d);
  float m = dec_f(menc[d * Hh + hh]);
  float ex = expf(ev[idx] - m);
  ev[idx] = ex;
  atomicAdd(&denom[d * Hh + hh], ex);
}

// ---------------- CSR build (dst-sorted) ----------------
__global__ void hist_k(const int* __restrict__ ei, int* __restrict__ count) {
  int e = blockIdx.x * blockDim.x + threadIdx.x;
  if (e >= E_TOT) return;
  int s, d; edge_sd(ei, e, s, d);
  atomicAdd(&count[d], 1);
}

__global__ __launch_bounds__(1024) void scan_k(const int* __restrict__ count,
                                               int* __restrict__ rowstart,
                                               int N, int total) {
  __shared__ int sums[1024];
  __shared__ int carry_s;
  int t = threadIdx.x;
  if (t == 0) carry_s = 0;
  __syncthreads();
  for (int base = 0; base < N; base += 1024) {
    int i = base + t;
    int c = (i < N) ? count[i] : 0;
    sums[t] = c;
    __syncthreads();
    for (int off = 1; off < 1024; off <<= 1) {
      int v = (t >= off) ? sums[t - off] : 0;
      __syncthreads();
      sums[t] += v;
      __syncthreads();
    }
    int carry = carry_s;
    if (i < N) rowstart[i] = carry + sums[t] - c;  // exclusive
    __syncthreads();
    if (t == 1023) carry_s = carry + sums[1023];
    __syncthreads();
  }
  if (t == 0) rowstart[N] = total;
}

__global__ void scatter_k(const int* __restrict__ ei,
                          const int* __restrict__ rowstart,
                          int* __restrict__ cursor,
                          int* __restrict__ csr_src, int* __restrict__ csr_eid) {
  int e = blockIdx.x * blockDim.x + threadIdx.x;
  if (e >= E_TOT) return;
  int s, d; edge_sd(ei, e, s, d);
  int pos = rowstart[d] + atomicAdd(&cursor[d], 1);
  csr_src[pos] = s;
  csr_eid[pos] = e;
}

// ---------------- aggregation: out[n,:] = sum_in alpha * h[src,:] (+bias, act) ----
// SPLIT: write f16 hi/lo (feeds next GEMM) instead of f32.
template <int FT, bool ELU, bool SPLIT>
__global__ void aggregate_k(const float* __restrict__ hsrc,
                            const float* __restrict__ ev,
                            const float* __restrict__ denom,
                            const float* __restrict__ bias,
                            const int* __restrict__ rowstart,
                            const int* __restrict__ csr_src,
                            const int* __restrict__ csr_eid,
                            float* __restrict__ out,
                            _Float16* __restrict__ ohi, _Float16* __restrict__ olo,
                            int Hh, int C) {
  const int n = blockIdx.x;
  const int t = threadIdx.x;
  const int F = Hh * C;
  const int f0 = t * FT;
  const int hh = f0 / C;                       // FT divides C -> no straddle
  const float inv = 1.f / (denom[n * Hh + hh] + 1e-16f);
  float acc[FT];
#pragma unroll
  for (int i = 0; i < FT; i++) acc[i] = 0.f;
  const int j0 = rowstart[n], j1 = rowstart[n + 1];
  for (int j = j0; j < j1; j++) {
    int s = csr_src[j];
    int eid = csr_eid[j];
    float wgt = ev[eid * Hh + hh] * inv;
    const float* hp = hsrc + (size_t)s * F + f0;
#pragma unroll
    for (int i = 0; i < FT; i += 4) {
      float4 v = *(const float4*)(hp + i);
      acc[i]     = fmaf(wgt, v.x, acc[i]);
      acc[i + 1] = fmaf(wgt, v.y, acc[i + 1]);
      acc[i + 2] = fmaf(wgt, v.z, acc[i + 2]);
      acc[i + 3] = fmaf(wgt, v.w, acc[i + 3]);
    }
  }
  if (SPLIT) {
    f16x8 h, l;
#pragma unroll
    for (int i = 0; i < FT; i++) {
      float o = acc[i] + bias[f0 + i];
      if (ELU) o = o > 0.f ? o : expm1f(o);
      _Float16 hv = (_Float16)o;
      h[i & 7] = hv;
      l[i & 7] = (_Float16)(o - (float)hv);
    }
    *(f16x8*)&ohi[(size_t)n * F + f0] = h;
    *(f16x8*)&olo[(size_t)n * F + f0] = l;
  } else {
#pragma unroll
    for (int i = 0; i < FT; i++) {
      float o = acc[i] + bias[f0 + i];
      if (ELU) o = o > 0.f ? o : expm1f(o);
      out[(size_t)n * F + f0 + i] = o;
    }
  }
}

// ---------------- launch ----------------
extern "C" void kernel_launch(void* const* d_in, const int* in_sizes, int n_in,
                              void* d_out, int out_size, void* d_ws, size_t ws_size,
                              hipStream_t stream) {
  const float* x   = (const float*)d_in[0];
  const int*   ei  = (const int*)d_in[1];   // [2, 160000]; JAX x64 off -> int32
  const float* W1  = (const float*)d_in[2];
  const float* as1 = (const float*)d_in[3];
  const float* ad1 = (const float*)d_in[4];
  const float* b1  = (const float*)d_in[5];
  const float* W2  = (const float*)d_in[6];
  const float* as2 = (const float*)d_in[7];
  const float* ad2 = (const float*)d_in[8];
  const float* b2  = (const float*)d_in[9];
  float* out = (float*)d_out;

  // bump allocator on workspace (everything rebuilt every call; ws is poisoned)
  char* p = (char*)d_ws;
  auto alloc = [&](size_t bytes) {
    char* r = p;
    p += (bytes + 255) & ~(size_t)255;
    return r;
  };
  float*     h1    = (float*)alloc((size_t)N_NODES * F1 * 4);      // 81.9 MB
  _Float16*  xhi   = (_Float16*)alloc((size_t)N_NODES * IN_DIM * 2);
  _Float16*  xlo   = (_Float16*)alloc((size_t)N_NODES * IN_DIM * 2);
  _Float16*  W1hi  = (_Float16*)alloc((size_t)IN_DIM * F1 * 2);    // [F1][IN_DIM]
  _Float16*  W1lo  = (_Float16*)alloc((size_t)IN_DIM * F1 * 2);
  _Float16*  W2hi  = (_Float16*)alloc((size_t)F1 * C2 * 2);        // [C2][F1]
  _Float16*  W2lo  = (_Float16*)alloc((size_t)F1 * C2 * 2);
  _Float16*  h2hi  = (_Float16*)alloc((size_t)N_NODES * F1 * 2);   // 41 MB
  _Float16*  h2lo  = (_Float16*)alloc((size_t)N_NODES * F1 * 2);
  float*     als   = (float*)alloc((size_t)N_NODES * H1 * 4);
  float*     ald   = (float*)alloc((size_t)N_NODES * H1 * 4);
  unsigned*  menc  = (unsigned*)alloc((size_t)N_NODES * H1 * 4);
  float*     denom = (float*)alloc((size_t)N_NODES * H1 * 4);
  float*     ev    = (float*)alloc((size_t)E_TOT * H1 * 4);
  int*       count    = (int*)alloc((size_t)N_NODES * 4);
  int*       rowstart = (int*)alloc((size_t)(N_NODES + 1) * 4);
  int*       cursor   = (int*)alloc((size_t)N_NODES * 4);
  int*       csr_src  = (int*)alloc((size_t)E_TOT * 4);
  int*       csr_eid  = (int*)alloc((size_t)E_TOT * 4);
  float*     h3 = h1;  // h1 dead after layer-1 aggregation; alias for GEMM2 out

  const int EB = (E_TOT + 255) / 256;

  // CSR by destination (same graph both layers)
  hipMemsetAsync(count, 0, (size_t)N_NODES * 4, stream);
  hipMemsetAsync(cursor, 0, (size_t)N_NODES * 4, stream);
  hist_k<<<EB, 256, 0, stream>>>(ei, count);
  scan_k<<<1, 1024, 0, stream>>>(count, rowstart, N_NODES, E_TOT);
  scatter_k<<<EB, 256, 0, stream>>>(ei, rowstart, cursor, csr_src, csr_eid);

  // input conversions
  split_k<<<(N_NODES * IN_DIM / 4 + 255) / 256, 256, 0, stream>>>(x, xhi, xlo,
                                                                  N_NODES * IN_DIM / 4);
  tsplit_k<<<dim3(F1 / 32, IN_DIM / 32), dim3(32, 8), 0, stream>>>(W1, W1hi, W1lo,
                                                                   IN_DIM, F1);
  tsplit_k<<<dim3(C2 / 32, F1 / 32), dim3(32, 8), 0, stream>>>(W2, W2hi, W2lo,
                                                               F1, C2);

  // ---- layer 1 ----
  gemm_sf16<<<dim3(F1 / 128, (N_NODES + 127) / 128), 256, 0, stream>>>(
      xhi, xlo, W1hi, W1lo, h1, N_NODES, F1, IN_DIM);
  attn_logits<<<(N_NODES * H1) / 4, 256, 0, stream>>>(h1, as1, ad1, als, ald,
                                                      N_NODES * H1, H1, C1);
  hipMemsetAsync(menc, 0, (size_t)N_NODES * H1 * 4, stream);
  hipMemsetAsync(denom, 0, (size_t)N_NODES * H1 * 4, stream);
  edge_max_k<<<(E_TOT * H1 + 255) / 256, 256, 0, stream>>>(ei, als, ald, ev, menc, H1);
  edge_exp_k<<<(E_TOT * H1 + 255) / 256, 256, 0, stream>>>(ei, menc, ev, denom, H1);
  aggregate_k<8, true, true><<<N_NODES, 256, 0, stream>>>(
      h1, ev, denom, b1, rowstart, csr_src, csr_eid, nullptr, h2hi, h2lo, H1, C1);

  // ---- layer 2 ----
  gemm_sf16<<<dim3(C2 / 128, (N_NODES + 127) / 128), 256, 0, stream>>>(
      h2hi, h2lo, W2hi, W2lo, h3, N_NODES, C2, F1);
  attn_logits<<<N_NODES / 4, 256, 0, stream>>>(h3, as2, ad2, als, ald,
                                               N_NODES, 1, C2);
  hipMemsetAsync(menc, 0, (size_t)N_NODES * 4, stream);
  hipMemsetAsync(denom, 0, (size_t)N_NODES * 4, stream);
  edge_max_k<<<EB, 256, 0, stream>>>(ei, als, ald, ev, menc, 1);
  edge_exp_k<<<EB, 256, 0, stream>>>(ei, menc, ev, denom, 1);
  aggregate_k<4, false, false><<<N_NODES, 192, 0, stream>>>(
      h3, ev, denom, b2, rowstart, csr_src, csr_eid, out, nullptr, nullptr, 1, C2);
}